// Round 5
// baseline (94.298 us; speedup 1.0000x reference)
//
#include <hip/hip_runtime.h>

typedef _Float16 f16x4 __attribute__((ext_vector_type(4)));
typedef __fp16 fp16x2 __attribute__((ext_vector_type(2)));   // cvt_pkrtz return type
typedef float f32x4 __attribute__((ext_vector_type(4)));

#define NBUCKETS 256
#define WT_OFF 1024          // weight-frag table offset in d_ws (bytes)
#define SSTR 84              // sr/sd row stride in halves (168B, balanced for b64)
#define HSTR 56              // ht x-stride in halves (112B, balanced for b64)
#define PLANE (64 * HSTR)    // one quantity's ht plane, in halves

// ---- pre-kernel: zero buckets + build the (shared) weight fragment ----
// Banded weights are translation-invariant: both the horizontal B-frag and the
// vertical A-frag reduce to  wf[kk][j] = w1[4g + j + 16kk - ln]  (0 outside band).
__global__ void ssim_pre(const float* __restrict__ win, float* __restrict__ ws)
{
    int lane = threadIdx.x;            // 64 threads
#pragma unroll
    for (int i = 0; i < 4; ++i) ws[lane + 64 * i] = 0.f;   // zero buckets

    float w1[11];
#pragma unroll
    for (int i = 0; i < 11; ++i) {
        float s = 0.f;
#pragma unroll
        for (int j = 0; j < 11; ++j) s += win[i * 11 + j];
        w1[i] = s;                     // 1D gaussian (row sums; sum==1)
    }
    int g = lane >> 4, ln = lane & 15;
    _Float16* wt = (_Float16*)((char*)ws + WT_OFF) + lane * 8;
#pragma unroll
    for (int kk = 0; kk < 2; ++kk)
#pragma unroll
        for (int j = 0; j < 4; ++j) {
            int idx = 4 * g + j + 16 * kk - ln;
            wt[kk * 4 + j] = (_Float16)((idx >= 0 && idx < 11) ? w1[idx] : 0.f);
        }
}

// ---- main: 64x32 output tile per block, 8 waves ----
__global__ __launch_bounds__(512, 6) void ssim_main(
    const float* __restrict__ raw, const float* __restrict__ dst,
    const float* __restrict__ ws_ro, float* __restrict__ buckets)
{
    __shared__ __align__(16) _Float16 sr[48 * SSTR];
    __shared__ __align__(16) _Float16 sd[48 * SSTR];
    __shared__ __align__(16) _Float16 ht[5 * PLANE];   // [q][x][r] transposed H

    const int tid = threadIdx.x;
    const int wv = tid >> 6;
    const int lane = tid & 63;
    const int g = lane >> 4;
    const int ln = lane & 15;
    const int nt = wv & 3;             // this wave's x-column tile (both phases)

    const int gx0 = blockIdx.x * 64;
    const int gy0 = blockIdx.y * 32;
    const long ioff = (long)blockIdx.z * (512 * 512);
    const float* rb = raw + ioff;
    const float* db = dst + ioff;

    // shared weight fragments (2 x f16x4 per lane, L2-hot 1KB table)
    const _Float16* wt = (const _Float16*)((const char*)ws_ro + WT_OFF) + lane * 8;
    f16x4 wf0 = *(const f16x4*)(wt);
    f16x4 wf1 = *(const f16x4*)(wt + 4);

    // ---- staging: 48 rows x {r,d} x 20 float4 chunks = 1920 tasks ----
    // Clamped addressing: halo junk is finite and only meets zero weights or
    // discarded outputs, so no interior/edge branch and no zero-fill needed.
    float4 fv[4];
    _Float16* dp[4];
#pragma unroll
    for (int k = 0; k < 4; ++k) {
        int t = tid + 512 * k;
        if (k < 3 || t < 1920) {
            int chunk = t % 20;
            int sub = t / 20;          // 0..95
            int arr = sub & 1;
            int row = sub >> 1;        // 0..47
            int gy = gy0 + row;  if (gy > 511) gy = 511;
            int gxc = gx0 + 4 * chunk; if (gxc > 508) gxc = 508;
            fv[k] = *reinterpret_cast<const float4*>((arr ? db : rb) + (long)gy * 512 + gxc);
            dp[k] = (arr ? sd : sr) + row * SSTR + chunk * 4;
        } else {
            dp[k] = nullptr;
        }
    }
#pragma unroll
    for (int k = 0; k < 4; ++k) {
        if (dp[k]) {
            union { fp16x2 h2[2]; uint2 u; } pk;
            pk.h2[0] = __builtin_amdgcn_cvt_pkrtz(fv[k].x, fv[k].y);
            pk.h2[1] = __builtin_amdgcn_cvt_pkrtz(fv[k].z, fv[k].w);
            *reinterpret_cast<uint2*>(dp[k]) = pk.u;
        }
    }
    __syncthreads();

    // ---- phase 2: horizontal conv via mfma(X, Wh); banded -> 2 k-slices ----
    // units u = mt*4 + nt', 12 total; wave w takes u=w (and u=w+8 if w<4);
    // both share nt' = w&3, so one weight frag pair per wave.
    for (int u = wv; u < 12; u += 8) {
        int mt = u >> 2;               // 0,1,2  (input-row tile)
        f32x4 a0 = {0,0,0,0}, a1 = {0,0,0,0}, a2 = {0,0,0,0},
              a3 = {0,0,0,0}, a4 = {0,0,0,0};
        int row = ln + 16 * mt;
        const _Float16* pr = sr + row * SSTR + 16 * nt + 4 * g;
        const _Float16* pd = sd + row * SSTR + 16 * nt + 4 * g;
#pragma unroll
        for (int kk = 0; kk < 2; ++kk) {
            f16x4 rA = *(const f16x4*)(pr + 16 * kk);
            f16x4 dA = *(const f16x4*)(pd + 16 * kk);
            f16x4 wf = kk ? wf1 : wf0;
            f16x4 rr = rA * rA, dd = dA * dA, rd = rA * dA;
            a0 = __builtin_amdgcn_mfma_f32_16x16x16f16(rA, wf, a0, 0, 0, 0);
            a1 = __builtin_amdgcn_mfma_f32_16x16x16f16(dA, wf, a1, 0, 0, 0);
            a2 = __builtin_amdgcn_mfma_f32_16x16x16f16(rr, wf, a2, 0, 0, 0);
            a3 = __builtin_amdgcn_mfma_f32_16x16x16f16(dd, wf, a3, 0, 0, 0);
            a4 = __builtin_amdgcn_mfma_f32_16x16x16f16(rd, wf, a4, 0, 0, 0);
        }
        int x = ln + 16 * nt;          // D col (global-x within tile)
        int r0 = 4 * g + 16 * mt;      // D first row (input-row index)
        _Float16* hb = ht + x * HSTR + r0;
#define STH(Q, A)                                                          \
        {   union { fp16x2 h2[2]; uint2 u; } pk;                           \
            pk.h2[0] = __builtin_amdgcn_cvt_pkrtz(A[0], A[1]);             \
            pk.h2[1] = __builtin_amdgcn_cvt_pkrtz(A[2], A[3]);             \
            *reinterpret_cast<uint2*>(hb + (Q) * PLANE) = pk.u; }
        STH(0, a0) STH(1, a1) STH(2, a2) STH(3, a3) STH(4, a4)
#undef STH
    }
    __syncthreads();

    // ---- phase 3: vertical conv via mfma(Wv, H); banded -> 2 k-slices ----
    const int mtv = wv >> 2;           // 0,1 (output-row tile)
    f32x4 v0 = {0,0,0,0}, v1 = {0,0,0,0}, v2 = {0,0,0,0},
          v3 = {0,0,0,0}, v4 = {0,0,0,0};
    {
        int x = ln + 16 * nt;
        const _Float16* hb = ht + x * HSTR + 16 * mtv + 4 * g;
#pragma unroll
        for (int kk = 0; kk < 2; ++kk) {
            const _Float16* hp = hb + 16 * kk;
            f16x4 wf = kk ? wf1 : wf0;
            f16x4 B0 = *(const f16x4*)(hp + 0 * PLANE);
            f16x4 B1 = *(const f16x4*)(hp + 1 * PLANE);
            f16x4 B2 = *(const f16x4*)(hp + 2 * PLANE);
            f16x4 B3 = *(const f16x4*)(hp + 3 * PLANE);
            f16x4 B4 = *(const f16x4*)(hp + 4 * PLANE);
            v0 = __builtin_amdgcn_mfma_f32_16x16x16f16(wf, B0, v0, 0, 0, 0);
            v1 = __builtin_amdgcn_mfma_f32_16x16x16f16(wf, B1, v1, 0, 0, 0);
            v2 = __builtin_amdgcn_mfma_f32_16x16x16f16(wf, B2, v2, 0, 0, 0);
            v3 = __builtin_amdgcn_mfma_f32_16x16x16f16(wf, B3, v3, 0, 0, 0);
            v4 = __builtin_amdgcn_mfma_f32_16x16x16f16(wf, B4, v4, 0, 0, 0);
        }
    }

    // ---- SSIM epilogue: lane holds 4 outputs (y=4g+j+16mtv, x=ln+16nt) ----
    float lsum = 0.f;
    {
        int ox = gx0 + ln + 16 * nt;
        int oy0 = gy0 + 4 * g + 16 * mtv;
        if (ox < 502) {
#pragma unroll
            for (int j = 0; j < 4; ++j) {
                if (oy0 + j < 502) {
                    float m1 = v0[j], m2 = v1[j];
                    float m1s = m1 * m1, m2s = m2 * m2, m12 = m1 * m2;
                    float va = v2[j] - m1s, vb = v3[j] - m2s, cv = v4[j] - m12;
                    float num = (2.f * m12 + 6.5025f) * (2.f * cv + 58.5225f);
                    float den = (m1s + m2s + 6.5025f) * (va + vb + 58.5225f);
                    lsum += __fdividef(num, den);
                }
            }
        }
    }
    // per-wave reduce + direct scattered atomic (no extra barrier)
#pragma unroll
    for (int off = 32; off; off >>= 1) lsum += __shfl_down(lsum, off);
    if (lane == 0) {
        int bucket = ((blockIdx.x + (blockIdx.y << 3)) * 8 + wv) & (NBUCKETS - 1);
        atomicAdd(&buckets[bucket], lsum);
    }
}

__global__ void ssim_finalize(const float* __restrict__ buckets,
                              float* __restrict__ out, float inv)
{
    int t = threadIdx.x;
    float s = 0.f;
    for (int i = t; i < NBUCKETS; i += 64) s += buckets[i];
#pragma unroll
    for (int off = 32; off; off >>= 1) s += __shfl_down(s, off);
    if (t == 0) out[0] = s * inv;
}

extern "C" void kernel_launch(void* const* d_in, const int* in_sizes, int n_in,
                              void* d_out, int out_size, void* d_ws, size_t ws_size,
                              hipStream_t stream) {
    const float* raw = (const float*)d_in[0];
    const float* dst = (const float*)d_in[1];
    const float* win = (const float*)d_in[2];
    float* out = (float*)d_out;
    float* ws = (float*)d_ws;

    int nimg = in_sizes[0] / (512 * 512);     // B*C = 48
    float inv = 1.0f / ((float)nimg * 502.f * 502.f);

    ssim_pre<<<1, 64, 0, stream>>>(win, ws);
    dim3 grid(8, 16, nimg);                   // 64x32 tiles
    ssim_main<<<grid, 512, 0, stream>>>(raw, dst, ws, ws);
    ssim_finalize<<<1, 64, 0, stream>>>(ws, out, inv);
}

// Round 6
// 57.014 us; speedup vs baseline: 1.6539x; 1.6539x over previous
//
#include <hip/hip_runtime.h>

typedef _Float16 f16x4 __attribute__((ext_vector_type(4)));
typedef __fp16 fp16x2 __attribute__((ext_vector_type(2)));   // cvt_pkrtz return type
typedef float f32x4 __attribute__((ext_vector_type(4)));

#define NBUCKETS 256
#define WT_OFF 1024          // weight-frag table offset in d_ws (bytes)
#define SSTR 80              // sr/sd row stride in halves (40 words -> uniform bank use)

// ---- pre-kernel: zero buckets + build shared weight fragment ----
// Banded, translation-invariant: wf[kk][j] = w1[4g + j + 16kk - ln] (0 outside band).
// Serves as horizontal B-frag AND vertical A-frag for all tiles (validated R3/R5).
__global__ void ssim_pre(const float* __restrict__ win, float* __restrict__ ws)
{
    int lane = threadIdx.x;            // 64 threads
#pragma unroll
    for (int i = 0; i < 4; ++i) ws[lane + 64 * i] = 0.f;   // zero buckets

    float w1[11];
#pragma unroll
    for (int i = 0; i < 11; ++i) {
        float s = 0.f;
#pragma unroll
        for (int j = 0; j < 11; ++j) s += win[i * 11 + j];
        w1[i] = s;                     // 1D gaussian (row sums; sum==1)
    }
    int g = lane >> 4, ln = lane & 15;
    _Float16* wt = (_Float16*)((char*)ws + WT_OFF) + lane * 8;
#pragma unroll
    for (int kk = 0; kk < 2; ++kk)
#pragma unroll
        for (int j = 0; j < 4; ++j) {
            int idx = 4 * g + j + 16 * kk - ln;
            wt[kk * 4 + j] = (_Float16)((idx >= 0 && idx < 11) ? w1[idx] : 0.f);
        }
}

// ---- main: 64x32 output tile, 4 waves; ONE barrier, H kept in registers ----
// Crux: mfma 16x16x16 D-frag (col=ln,row=4g+j) == B-frag (col=ln,k=4g+j), so each
// wave's horizontal-conv output feeds the vertical conv directly via f32->f16 cvt.
__global__ __launch_bounds__(256, 4) void ssim_main(
    const float* __restrict__ raw, const float* __restrict__ dst,
    const float* __restrict__ ws_ro, float* __restrict__ buckets)
{
    __shared__ __align__(16) _Float16 sr[48 * SSTR];
    __shared__ __align__(16) _Float16 sd[48 * SSTR];

    const int tid = threadIdx.x;
    const int wv = tid >> 6;           // 0..3 = this wave's 16-wide x-strip
    const int lane = tid & 63;
    const int g = lane >> 4;
    const int ln = lane & 15;
    const int nt = wv;

    const int gx0 = blockIdx.x * 64;
    const int gy0 = blockIdx.y * 32;
    const long ioff = (long)blockIdx.z * (512 * 512);
    const float* rb = raw + ioff;
    const float* db = dst + ioff;

    const _Float16* wt = (const _Float16*)((const char*)ws_ro + WT_OFF) + lane * 8;
    f16x4 wf0 = *(const f16x4*)(wt);
    f16x4 wf1 = *(const f16x4*)(wt + 4);

    // ---- staging: 48 rows x 20 float4 chunks x {r,d} = 1920 tasks, clamped ----
    // Junk (clamped halo / rows 42-47 / cols 74-79) is finite and only ever meets
    // zero band-weights or discarded outputs.
    float4 fv[8];
    _Float16* dp[8];
#pragma unroll
    for (int k = 0; k < 8; ++k) {
        int t = tid + 256 * k;
        if (k < 7 || t < 1920) {
            int chunk = t % 20;
            int sub = t / 20;          // 0..95
            int arr = sub & 1;
            int row = sub >> 1;        // 0..47
            int gy = gy0 + row;  if (gy > 511) gy = 511;
            int gxc = gx0 + 4 * chunk; if (gxc > 508) gxc = 508;
            fv[k] = *reinterpret_cast<const float4*>((arr ? db : rb) + (long)gy * 512 + gxc);
            dp[k] = (arr ? sd : sr) + row * SSTR + chunk * 4;
        } else {
            dp[k] = nullptr;
        }
    }
#pragma unroll
    for (int k = 0; k < 8; ++k) {
        if (dp[k]) {
            union { fp16x2 h2[2]; uint2 u; } pk;
            pk.h2[0] = __builtin_amdgcn_cvt_pkrtz(fv[k].x, fv[k].y);
            pk.h2[1] = __builtin_amdgcn_cvt_pkrtz(fv[k].z, fv[k].w);
            *reinterpret_cast<uint2*>(dp[k]) = pk.u;
        }
    }
    __syncthreads();

    // ---- horizontal conv H(mt) -> register f16 frags (no LDS, no barrier) ----
    f16x4 hf0[5], hf1[5], hf2[5];
#define COMP_H(HF, MT)                                                        \
    {                                                                         \
        f32x4 a0 = {0,0,0,0}, a1 = {0,0,0,0}, a2 = {0,0,0,0},                 \
              a3 = {0,0,0,0}, a4 = {0,0,0,0};                                 \
        const _Float16* pr = sr + (ln + 16 * (MT)) * SSTR + 16 * nt + 4 * g;  \
        const _Float16* pd = sd + (ln + 16 * (MT)) * SSTR + 16 * nt + 4 * g;  \
        _Pragma("unroll")                                                     \
        for (int kk = 0; kk < 2; ++kk) {                                      \
            f16x4 rA = *(const f16x4*)(pr + 16 * kk);                         \
            f16x4 dA = *(const f16x4*)(pd + 16 * kk);                         \
            f16x4 wf = kk ? wf1 : wf0;                                        \
            f16x4 rr = rA * rA, dd = dA * dA, rd = rA * dA;                   \
            a0 = __builtin_amdgcn_mfma_f32_16x16x16f16(rA, wf, a0, 0, 0, 0);  \
            a1 = __builtin_amdgcn_mfma_f32_16x16x16f16(dA, wf, a1, 0, 0, 0);  \
            a2 = __builtin_amdgcn_mfma_f32_16x16x16f16(rr, wf, a2, 0, 0, 0);  \
            a3 = __builtin_amdgcn_mfma_f32_16x16x16f16(dd, wf, a3, 0, 0, 0);  \
            a4 = __builtin_amdgcn_mfma_f32_16x16x16f16(rd, wf, a4, 0, 0, 0);  \
        }                                                                     \
        HF[0] = f16x4{(_Float16)a0[0], (_Float16)a0[1], (_Float16)a0[2], (_Float16)a0[3]}; \
        HF[1] = f16x4{(_Float16)a1[0], (_Float16)a1[1], (_Float16)a1[2], (_Float16)a1[3]}; \
        HF[2] = f16x4{(_Float16)a2[0], (_Float16)a2[1], (_Float16)a2[2], (_Float16)a2[3]}; \
        HF[3] = f16x4{(_Float16)a3[0], (_Float16)a3[1], (_Float16)a3[2], (_Float16)a3[3]}; \
        HF[4] = f16x4{(_Float16)a4[0], (_Float16)a4[1], (_Float16)a4[2], (_Float16)a4[3]}; \
    }

    COMP_H(hf0, 0)
    COMP_H(hf1, 1)
    COMP_H(hf2, 2)
#undef COMP_H

    // ---- vertical conv O(mtv) + SSIM epilogue, all in registers ----
    float lsum = 0.f;
    const int ox = gx0 + 16 * nt + ln;
#define COMP_O(HA, HB, MTV)                                                   \
    {                                                                         \
        f32x4 z = {0, 0, 0, 0};                                               \
        f32x4 v0 = __builtin_amdgcn_mfma_f32_16x16x16f16(wf0, HA[0], z, 0, 0, 0); \
        f32x4 v1 = __builtin_amdgcn_mfma_f32_16x16x16f16(wf0, HA[1], z, 0, 0, 0); \
        f32x4 v2 = __builtin_amdgcn_mfma_f32_16x16x16f16(wf0, HA[2], z, 0, 0, 0); \
        f32x4 v3 = __builtin_amdgcn_mfma_f32_16x16x16f16(wf0, HA[3], z, 0, 0, 0); \
        f32x4 v4 = __builtin_amdgcn_mfma_f32_16x16x16f16(wf0, HA[4], z, 0, 0, 0); \
        v0 = __builtin_amdgcn_mfma_f32_16x16x16f16(wf1, HB[0], v0, 0, 0, 0);  \
        v1 = __builtin_amdgcn_mfma_f32_16x16x16f16(wf1, HB[1], v1, 0, 0, 0);  \
        v2 = __builtin_amdgcn_mfma_f32_16x16x16f16(wf1, HB[2], v2, 0, 0, 0);  \
        v3 = __builtin_amdgcn_mfma_f32_16x16x16f16(wf1, HB[3], v3, 0, 0, 0);  \
        v4 = __builtin_amdgcn_mfma_f32_16x16x16f16(wf1, HB[4], v4, 0, 0, 0);  \
        int oy0 = gy0 + 16 * (MTV) + 4 * g;                                   \
        if (ox < 502) {                                                       \
            _Pragma("unroll")                                                 \
            for (int j = 0; j < 4; ++j) {                                     \
                if (oy0 + j < 502) {                                          \
                    float m1 = v0[j], m2 = v1[j];                             \
                    float m1s = m1 * m1, m2s = m2 * m2, m12 = m1 * m2;        \
                    float va = v2[j] - m1s, vb = v3[j] - m2s, cv = v4[j] - m12; \
                    float num = (2.f * m12 + 6.5025f) * (2.f * cv + 58.5225f); \
                    float den = (m1s + m2s + 6.5025f) * (va + vb + 58.5225f); \
                    lsum += __fdividef(num, den);                             \
                }                                                             \
            }                                                                 \
        }                                                                     \
    }

    COMP_O(hf0, hf1, 0)
    COMP_O(hf1, hf2, 1)
#undef COMP_O

    // per-wave reduce + scattered atomic (no extra barrier)
#pragma unroll
    for (int off = 32; off; off >>= 1) lsum += __shfl_down(lsum, off);
    if (lane == 0) {
        int bucket = ((blockIdx.x + (blockIdx.y << 3) + blockIdx.z * 131) * 4 + wv) & (NBUCKETS - 1);
        atomicAdd(&buckets[bucket], lsum);
    }
}

__global__ void ssim_finalize(const float* __restrict__ buckets,
                              float* __restrict__ out, float inv)
{
    int t = threadIdx.x;
    float s = 0.f;
    for (int i = t; i < NBUCKETS; i += 64) s += buckets[i];
#pragma unroll
    for (int off = 32; off; off >>= 1) s += __shfl_down(s, off);
    if (t == 0) out[0] = s * inv;
}

extern "C" void kernel_launch(void* const* d_in, const int* in_sizes, int n_in,
                              void* d_out, int out_size, void* d_ws, size_t ws_size,
                              hipStream_t stream) {
    const float* raw = (const float*)d_in[0];
    const float* dst = (const float*)d_in[1];
    const float* win = (const float*)d_in[2];
    float* out = (float*)d_out;
    float* ws = (float*)d_ws;

    int nimg = in_sizes[0] / (512 * 512);     // B*C = 48
    float inv = 1.0f / ((float)nimg * 502.f * 502.f);

    ssim_pre<<<1, 64, 0, stream>>>(win, ws);
    dim3 grid(8, 16, nimg);                   // 64x32 tiles, 4 waves each
    ssim_main<<<grid, 256, 0, stream>>>(raw, dst, ws, ws);
    ssim_finalize<<<1, 64, 0, stream>>>(ws, out, inv);
}

// Round 7
// 42.584 us; speedup vs baseline: 2.2144x; 1.3389x over previous
//
#include <hip/hip_runtime.h>

typedef _Float16 f16x4 __attribute__((ext_vector_type(4)));
typedef __fp16 fp16x2 __attribute__((ext_vector_type(2)));   // cvt_pkrtz return type
typedef float f32x4 __attribute__((ext_vector_type(4)));

#define NBUCKETS 256
#define WT_OFF 1024          // weight-frag table offset in d_ws (bytes)
#define SSTR 80              // sr/sd row stride in halves
#define NT_Y 4               // vertical tiles per block

// ---- pre-kernel: zero buckets + build shared weight fragment ----
// Banded, translation-invariant: wf[kk][j] = w1[4g + j + 16kk - ln] (0 outside band).
// Serves as horizontal B-frag AND vertical A-frag for all tiles (validated R3/R5/R6).
__global__ void ssim_pre(const float* __restrict__ win, float* __restrict__ ws)
{
    int lane = threadIdx.x;            // 64 threads
#pragma unroll
    for (int i = 0; i < 4; ++i) ws[lane + 64 * i] = 0.f;   // zero buckets

    float w1[11];
#pragma unroll
    for (int i = 0; i < 11; ++i) {
        float s = 0.f;
#pragma unroll
        for (int j = 0; j < 11; ++j) s += win[i * 11 + j];
        w1[i] = s;                     // 1D gaussian (row sums; sum==1)
    }
    int g = lane >> 4, ln = lane & 15;
    _Float16* wt = (_Float16*)((char*)ws + WT_OFF) + lane * 8;
#pragma unroll
    for (int kk = 0; kk < 2; ++kk)
#pragma unroll
        for (int j = 0; j < 4; ++j) {
            int idx = 4 * g + j + 16 * kk - ln;
            wt[kk * 4 + j] = (_Float16)((idx >= 0 && idx < 11) ? w1[idx] : 0.f);
        }
}

__device__ __forceinline__ f16x4 cvt4(f32x4 a)
{
    union { fp16x2 h2[2]; f16x4 f; } u;
    u.h2[0] = __builtin_amdgcn_cvt_pkrtz(a[0], a[1]);
    u.h2[1] = __builtin_amdgcn_cvt_pkrtz(a[2], a[3]);
    return u.f;
}

// ---- main: 4 vertically-adjacent 64x32 tiles per block, register-prefetch pipeline.
// Quantities: mu1, mu2, A=conv((r+d)^2), B=conv((r-d)^2);
//   Err+Edd = (A+B)/2, 2*Erd = (A-B)/2.
__global__ __launch_bounds__(256, 4) void ssim_main(
    const float* __restrict__ raw, const float* __restrict__ dst,
    const float* __restrict__ ws_ro, float* __restrict__ buckets)
{
    __shared__ __align__(16) _Float16 sr[48 * SSTR];
    __shared__ __align__(16) _Float16 sd[48 * SSTR];

    const int tid = threadIdx.x;
    const int wv = tid >> 6;           // wave = 16-wide x-strip
    const int lane = tid & 63;
    const int g = lane >> 4;
    const int ln = lane & 15;
    const int nt = wv;

    const int gx0 = blockIdx.x * 64;
    const int ybase = blockIdx.y * NT_Y;        // first y-tile index
    const long ioff = (long)blockIdx.z * (512 * 512);
    const float* rb = raw + ioff;
    const float* db = dst + ioff;

    const _Float16* wt = (const _Float16*)((const char*)ws_ro + WT_OFF) + lane * 8;
    f16x4 wf0 = *(const f16x4*)(wt);
    f16x4 wf1 = *(const f16x4*)(wt + 4);

    // ---- per-thread staging task params (tile-invariant) ----
    // 1920 tasks = 48 rows x {r,d} x 20 float4 chunks; k==7 valid only for tid<128
    const bool v7 = (tid < 128);
    int srow[8]; const float* sbase[8]; _Float16* sdst[8];
#pragma unroll
    for (int k = 0; k < 8; ++k) {
        int t = tid + 256 * k;
        int chunk = t % 20;
        int sub = t / 20;
        int arr = sub & 1;
        srow[k] = sub >> 1;
        int gxc = gx0 + 4 * chunk; if (gxc > 508) gxc = 508;
        sbase[k] = (arr ? db : rb) + gxc;
        sdst[k] = (arr ? sd : sr) + (sub >> 1) * SSTR + chunk * 4;
    }

    float4 fv[8];
#define ISSUE_LOADS(YT)                                                       \
    { _Pragma("unroll")                                                       \
      for (int k = 0; k < 8; ++k) {                                           \
          if (k < 7 || v7) {                                                  \
              int gy = (YT) * 32 + srow[k]; if (gy > 511) gy = 511;           \
              fv[k] = *reinterpret_cast<const float4*>(sbase[k] + (long)gy * 512); \
          } } }

#define WRITE_LDS()                                                           \
    { _Pragma("unroll")                                                       \
      for (int k = 0; k < 8; ++k) {                                           \
          if (k < 7 || v7) {                                                  \
              union { fp16x2 h2[2]; uint2 u; } pk;                            \
              pk.h2[0] = __builtin_amdgcn_cvt_pkrtz(fv[k].x, fv[k].y);        \
              pk.h2[1] = __builtin_amdgcn_cvt_pkrtz(fv[k].z, fv[k].w);        \
              *reinterpret_cast<uint2*>(sdst[k]) = pk.u;                      \
          } } }

    float lsum = 0.f;
    const int ox = gx0 + 16 * nt + ln;

    ISSUE_LOADS(ybase)
    WRITE_LDS()
    __syncthreads();

#pragma unroll
    for (int it = 0; it < NT_Y; ++it) {
        if (it < NT_Y - 1) ISSUE_LOADS(ybase + it + 1)

        // ---- horizontal conv -> register f16 frags (4 quantities) ----
        f16x4 hf0[4], hf1[4], hf2[4];
#define COMP_H(HF, MT)                                                        \
        {                                                                     \
            f32x4 a0 = {0,0,0,0}, a1 = {0,0,0,0}, a2 = {0,0,0,0},             \
                  a3 = {0,0,0,0};                                             \
            const _Float16* pr = sr + (ln + 16 * (MT)) * SSTR + 16 * nt + 4 * g; \
            const _Float16* pd = sd + (ln + 16 * (MT)) * SSTR + 16 * nt + 4 * g; \
            _Pragma("unroll")                                                 \
            for (int kk = 0; kk < 2; ++kk) {                                  \
                f16x4 rA = *(const f16x4*)(pr + 16 * kk);                     \
                f16x4 dA = *(const f16x4*)(pd + 16 * kk);                     \
                f16x4 wf = kk ? wf1 : wf0;                                    \
                f16x4 sA = rA + dA, qA = rA - dA;                             \
                f16x4 ss = sA * sA, qq = qA * qA;                             \
                a0 = __builtin_amdgcn_mfma_f32_16x16x16f16(rA, wf, a0, 0, 0, 0); \
                a1 = __builtin_amdgcn_mfma_f32_16x16x16f16(dA, wf, a1, 0, 0, 0); \
                a2 = __builtin_amdgcn_mfma_f32_16x16x16f16(ss, wf, a2, 0, 0, 0); \
                a3 = __builtin_amdgcn_mfma_f32_16x16x16f16(qq, wf, a3, 0, 0, 0); \
            }                                                                 \
            HF[0] = cvt4(a0); HF[1] = cvt4(a1);                               \
            HF[2] = cvt4(a2); HF[3] = cvt4(a3);                               \
        }
        COMP_H(hf0, 0)
        COMP_H(hf1, 1)
        COMP_H(hf2, 2)
#undef COMP_H

        // ---- vertical conv + SSIM epilogue (registers only) ----
#define COMP_O(HA, HB, MTV)                                                   \
        {                                                                     \
            f32x4 z = {0, 0, 0, 0};                                           \
            f32x4 v0 = __builtin_amdgcn_mfma_f32_16x16x16f16(wf0, HA[0], z, 0, 0, 0); \
            f32x4 v1 = __builtin_amdgcn_mfma_f32_16x16x16f16(wf0, HA[1], z, 0, 0, 0); \
            f32x4 v2 = __builtin_amdgcn_mfma_f32_16x16x16f16(wf0, HA[2], z, 0, 0, 0); \
            f32x4 v3 = __builtin_amdgcn_mfma_f32_16x16x16f16(wf0, HA[3], z, 0, 0, 0); \
            v0 = __builtin_amdgcn_mfma_f32_16x16x16f16(wf1, HB[0], v0, 0, 0, 0); \
            v1 = __builtin_amdgcn_mfma_f32_16x16x16f16(wf1, HB[1], v1, 0, 0, 0); \
            v2 = __builtin_amdgcn_mfma_f32_16x16x16f16(wf1, HB[2], v2, 0, 0, 0); \
            v3 = __builtin_amdgcn_mfma_f32_16x16x16f16(wf1, HB[3], v3, 0, 0, 0); \
            int oy0 = (ybase + it) * 32 + 16 * (MTV) + 4 * g;                 \
            if (ox < 502) {                                                   \
                _Pragma("unroll")                                             \
                for (int j = 0; j < 4; ++j) {                                 \
                    if (oy0 + j < 502) {                                      \
                        float m1 = v0[j], m2 = v1[j], A = v2[j], B = v3[j];   \
                        float m1s = m1 * m1, m2s = m2 * m2, m12 = m1 * m2;    \
                        float num = (2.f * m12 + 6.5025f) *                   \
                                    (0.5f * (A - B) - 2.f * m12 + 58.5225f);  \
                        float den = (m1s + m2s + 6.5025f) *                   \
                                    (0.5f * (A + B) - m1s - m2s + 58.5225f);  \
                        lsum += __fdividef(num, den);                         \
                    }                                                         \
                }                                                             \
            }                                                                 \
        }
        COMP_O(hf0, hf1, 0)
        COMP_O(hf1, hf2, 1)
#undef COMP_O

        if (it < NT_Y - 1) {
            __syncthreads();       // all waves done reading this tile's LDS
            WRITE_LDS()            // waits on prefetch loads, writes next tile
            __syncthreads();
        }
    }

    // per-wave reduce + scattered atomic
#pragma unroll
    for (int off = 32; off; off >>= 1) lsum += __shfl_down(lsum, off);
    if (lane == 0) {
        int bucket = ((blockIdx.x + (blockIdx.y << 3) + blockIdx.z * 37) * 4 + wv) & (NBUCKETS - 1);
        atomicAdd(&buckets[bucket], lsum);
    }
#undef ISSUE_LOADS
#undef WRITE_LDS
}

__global__ void ssim_finalize(const float* __restrict__ buckets,
                              float* __restrict__ out, float inv)
{
    int t = threadIdx.x;
    float s = 0.f;
    for (int i = t; i < NBUCKETS; i += 64) s += buckets[i];
#pragma unroll
    for (int off = 32; off; off >>= 1) s += __shfl_down(s, off);
    if (t == 0) out[0] = s * inv;
}

extern "C" void kernel_launch(void* const* d_in, const int* in_sizes, int n_in,
                              void* d_out, int out_size, void* d_ws, size_t ws_size,
                              hipStream_t stream) {
    const float* raw = (const float*)d_in[0];
    const float* dst = (const float*)d_in[1];
    const float* win = (const float*)d_in[2];
    float* out = (float*)d_out;
    float* ws = (float*)d_ws;

    int nimg = in_sizes[0] / (512 * 512);     // B*C = 48
    float inv = 1.0f / ((float)nimg * 502.f * 502.f);

    ssim_pre<<<1, 64, 0, stream>>>(win, ws);
    dim3 grid(8, 4, nimg);                    // x-tile, y-group(4 tiles), image
    ssim_main<<<grid, 256, 0, stream>>>(raw, dst, ws, ws);
    ssim_finalize<<<1, 64, 0, stream>>>(ws, out, inv);
}

// Round 8
// 41.044 us; speedup vs baseline: 2.2975x; 1.0375x over previous
//
#include <hip/hip_runtime.h>

typedef _Float16 f16x4 __attribute__((ext_vector_type(4)));
typedef __fp16 fp16x2 __attribute__((ext_vector_type(2)));   // cvt_pkrtz return type
typedef float f32x4 __attribute__((ext_vector_type(4)));

#define NBUCKETS 256
#define WT_OFF 1024          // weight-frag table offset in d_ws (bytes)
#define SSTR 80              // sr/sd row stride in halves
#define BUFH (48 * SSTR)     // one buffer, in halves
#define NT_Y 2               // vertical tiles per block

// ---- pre-kernel: zero buckets + build shared weight fragment ----
// Banded, translation-invariant: wf[kk][j] = w1[4g + j + 16kk - ln] (0 outside band).
// Serves as horizontal B-frag AND vertical A-frag for all tiles (validated R3/R5/R6).
__global__ void ssim_pre(const float* __restrict__ win, float* __restrict__ ws)
{
    int lane = threadIdx.x;            // 64 threads
#pragma unroll
    for (int i = 0; i < 4; ++i) ws[lane + 64 * i] = 0.f;   // zero buckets

    float w1[11];
#pragma unroll
    for (int i = 0; i < 11; ++i) {
        float s = 0.f;
#pragma unroll
        for (int j = 0; j < 11; ++j) s += win[i * 11 + j];
        w1[i] = s;                     // 1D gaussian (row sums; sum==1)
    }
    int g = lane >> 4, ln = lane & 15;
    _Float16* wt = (_Float16*)((char*)ws + WT_OFF) + lane * 8;
#pragma unroll
    for (int kk = 0; kk < 2; ++kk)
#pragma unroll
        for (int j = 0; j < 4; ++j) {
            int idx = 4 * g + j + 16 * kk - ln;
            wt[kk * 4 + j] = (_Float16)((idx >= 0 && idx < 11) ? w1[idx] : 0.f);
        }
}

__device__ __forceinline__ f16x4 cvt4(f32x4 a)
{
    union { fp16x2 h2[2]; f16x4 f; } u;
    u.h2[0] = __builtin_amdgcn_cvt_pkrtz(a[0], a[1]);
    u.h2[1] = __builtin_amdgcn_cvt_pkrtz(a[2], a[3]);
    return u.f;
}

// ---- main: 2 vertically-adjacent 64x32 tiles per block, double-buffered LDS,
// ONE barrier per tile. Quantities: mu1, mu2, A=conv((r+d)^2), B=conv((r-d)^2).
__global__ __launch_bounds__(256, 4) void ssim_main(
    const float* __restrict__ raw, const float* __restrict__ dst,
    const float* __restrict__ ws_ro, float* __restrict__ buckets)
{
    __shared__ __align__(16) _Float16 sr[2 * BUFH];
    __shared__ __align__(16) _Float16 sd[2 * BUFH];

    const int tid = threadIdx.x;
    const int wv = tid >> 6;           // wave = 16-wide x-strip
    const int lane = tid & 63;
    const int g = lane >> 4;
    const int ln = lane & 15;
    const int nt = wv;

    const int gx0 = blockIdx.x * 64;
    const int ybase = blockIdx.y * NT_Y;        // first y-tile index
    const long ioff = (long)blockIdx.z * (512 * 512);
    const float* rb = raw + ioff;
    const float* db = dst + ioff;

    const _Float16* wt = (const _Float16*)((const char*)ws_ro + WT_OFF) + lane * 8;
    f16x4 wf0 = *(const f16x4*)(wt);
    f16x4 wf1 = *(const f16x4*)(wt + 4);

    // ---- per-thread staging task params (tile-invariant) ----
    // 1920 tasks = 48 rows x {r,d} x 20 float4 chunks; k==7 valid only for tid<128
    const bool v7 = (tid < 128);
    int srow[8]; const float* sbase[8]; _Float16* sdst0[8];
#pragma unroll
    for (int k = 0; k < 8; ++k) {
        int t = tid + 256 * k;
        int chunk = t % 20;
        int sub = t / 20;
        int arr = sub & 1;
        srow[k] = sub >> 1;
        int gxc = gx0 + 4 * chunk; if (gxc > 508) gxc = 508;
        sbase[k] = (arr ? db : rb) + gxc;
        sdst0[k] = (arr ? sd : sr) + (sub >> 1) * SSTR + chunk * 4;
    }

    float4 fv[8];
#define ISSUE_LOADS(YT)                                                       \
    { _Pragma("unroll")                                                       \
      for (int k = 0; k < 8; ++k) {                                           \
          if (k < 7 || v7) {                                                  \
              int gy = (YT) * 32 + srow[k]; if (gy > 511) gy = 511;           \
              fv[k] = *reinterpret_cast<const float4*>(sbase[k] + (long)gy * 512); \
          } } }

#define WRITE_LDS(B)                                                          \
    { _Pragma("unroll")                                                       \
      for (int k = 0; k < 8; ++k) {                                           \
          if (k < 7 || v7) {                                                  \
              union { fp16x2 h2[2]; uint2 u; } pk;                            \
              pk.h2[0] = __builtin_amdgcn_cvt_pkrtz(fv[k].x, fv[k].y);        \
              pk.h2[1] = __builtin_amdgcn_cvt_pkrtz(fv[k].z, fv[k].w);        \
              *reinterpret_cast<uint2*>(sdst0[k] + (B) * BUFH) = pk.u;        \
          } } }

    float lsum = 0.f;
    const int ox = gx0 + 16 * nt + ln;

    ISSUE_LOADS(ybase)
    WRITE_LDS(0)
    __syncthreads();

#pragma unroll
    for (int it = 0; it < NT_Y; ++it) {
        if (it < NT_Y - 1) ISSUE_LOADS(ybase + it + 1)

        const _Float16* srb = sr + (it & 1) * BUFH;
        const _Float16* sdb = sd + (it & 1) * BUFH;

        // ---- horizontal conv -> register f16 frags (4 quantities) ----
        f16x4 hf0[4], hf1[4], hf2[4];
#define COMP_H(HF, MT)                                                        \
        {                                                                     \
            f32x4 a0 = {0,0,0,0}, a1 = {0,0,0,0}, a2 = {0,0,0,0},             \
                  a3 = {0,0,0,0};                                             \
            const _Float16* pr = srb + (ln + 16 * (MT)) * SSTR + 16 * nt + 4 * g; \
            const _Float16* pd = sdb + (ln + 16 * (MT)) * SSTR + 16 * nt + 4 * g; \
            _Pragma("unroll")                                                 \
            for (int kk = 0; kk < 2; ++kk) {                                  \
                f16x4 rA = *(const f16x4*)(pr + 16 * kk);                     \
                f16x4 dA = *(const f16x4*)(pd + 16 * kk);                     \
                f16x4 wf = kk ? wf1 : wf0;                                    \
                f16x4 sA = rA + dA, qA = rA - dA;                             \
                f16x4 ss = sA * sA, qq = qA * qA;                             \
                a0 = __builtin_amdgcn_mfma_f32_16x16x16f16(rA, wf, a0, 0, 0, 0); \
                a1 = __builtin_amdgcn_mfma_f32_16x16x16f16(dA, wf, a1, 0, 0, 0); \
                a2 = __builtin_amdgcn_mfma_f32_16x16x16f16(ss, wf, a2, 0, 0, 0); \
                a3 = __builtin_amdgcn_mfma_f32_16x16x16f16(qq, wf, a3, 0, 0, 0); \
            }                                                                 \
            HF[0] = cvt4(a0); HF[1] = cvt4(a1);                               \
            HF[2] = cvt4(a2); HF[3] = cvt4(a3);                               \
        }
        COMP_H(hf0, 0)
        COMP_H(hf1, 1)
        COMP_H(hf2, 2)
#undef COMP_H

        // ---- vertical conv + SSIM epilogue (registers only) ----
#define COMP_O(HA, HB, MTV)                                                   \
        {                                                                     \
            f32x4 z = {0, 0, 0, 0};                                           \
            f32x4 v0 = __builtin_amdgcn_mfma_f32_16x16x16f16(wf0, HA[0], z, 0, 0, 0); \
            f32x4 v1 = __builtin_amdgcn_mfma_f32_16x16x16f16(wf0, HA[1], z, 0, 0, 0); \
            f32x4 v2 = __builtin_amdgcn_mfma_f32_16x16x16f16(wf0, HA[2], z, 0, 0, 0); \
            f32x4 v3 = __builtin_amdgcn_mfma_f32_16x16x16f16(wf0, HA[3], z, 0, 0, 0); \
            v0 = __builtin_amdgcn_mfma_f32_16x16x16f16(wf1, HB[0], v0, 0, 0, 0); \
            v1 = __builtin_amdgcn_mfma_f32_16x16x16f16(wf1, HB[1], v1, 0, 0, 0); \
            v2 = __builtin_amdgcn_mfma_f32_16x16x16f16(wf1, HB[2], v2, 0, 0, 0); \
            v3 = __builtin_amdgcn_mfma_f32_16x16x16f16(wf1, HB[3], v3, 0, 0, 0); \
            int oy0 = (ybase + it) * 32 + 16 * (MTV) + 4 * g;                 \
            if (ox < 502) {                                                   \
                _Pragma("unroll")                                             \
                for (int j = 0; j < 4; ++j) {                                 \
                    if (oy0 + j < 502) {                                      \
                        float m1 = v0[j], m2 = v1[j], A = v2[j], B = v3[j];   \
                        float m1s = m1 * m1, m2s = m2 * m2, m12 = m1 * m2;    \
                        float num = (2.f * m12 + 6.5025f) *                   \
                                    (0.5f * (A - B) - 2.f * m12 + 58.5225f);  \
                        float den = (m1s + m2s + 6.5025f) *                   \
                                    (0.5f * (A + B) - m1s - m2s + 58.5225f);  \
                        lsum += __fdividef(num, den);                         \
                    }                                                         \
                }                                                             \
            }                                                                 \
        }
        COMP_O(hf0, hf1, 0)
        COMP_O(hf1, hf2, 1)
#undef COMP_O

        if (it < NT_Y - 1) {
            WRITE_LDS((it + 1) & 1)    // other buffer: no reader conflict
            __syncthreads();           // single barrier orders write -> read
        }
    }

    // per-wave reduce + scattered atomic
#pragma unroll
    for (int off = 32; off; off >>= 1) lsum += __shfl_down(lsum, off);
    if (lane == 0) {
        int bucket = ((blockIdx.x + (blockIdx.y << 3) + blockIdx.z * 67) * 4 + wv) & (NBUCKETS - 1);
        atomicAdd(&buckets[bucket], lsum);
    }
#undef ISSUE_LOADS
#undef WRITE_LDS
}

__global__ void ssim_finalize(const float* __restrict__ buckets,
                              float* __restrict__ out, float inv)
{
    int t = threadIdx.x;
    float s = 0.f;
    for (int i = t; i < NBUCKETS; i += 64) s += buckets[i];
#pragma unroll
    for (int off = 32; off; off >>= 1) s += __shfl_down(s, off);
    if (t == 0) out[0] = s * inv;
}

extern "C" void kernel_launch(void* const* d_in, const int* in_sizes, int n_in,
                              void* d_out, int out_size, void* d_ws, size_t ws_size,
                              hipStream_t stream) {
    const float* raw = (const float*)d_in[0];
    const float* dst = (const float*)d_in[1];
    const float* win = (const float*)d_in[2];
    float* out = (float*)d_out;
    float* ws = (float*)d_ws;

    int nimg = in_sizes[0] / (512 * 512);     // B*C = 48
    float inv = 1.0f / ((float)nimg * 502.f * 502.f);

    ssim_pre<<<1, 64, 0, stream>>>(win, ws);
    dim3 grid(8, 8, nimg);                    // x-tile, y-group(2 tiles), image
    ssim_main<<<grid, 256, 0, stream>>>(raw, dst, ws, ws);
    ssim_finalize<<<1, 64, 0, stream>>>(ws, out, inv);
}